// Round 13
// baseline (56.382 us; speedup 1.0000x reference)
//
#include <hip/hip_runtime.h>
#include <hip/hip_bf16.h>

typedef float f32x4 __attribute__((ext_vector_type(4)));
typedef float f32x2 __attribute__((ext_vector_type(2)));
typedef short bf16x8 __attribute__((ext_vector_type(8)));
typedef const __attribute__((address_space(1))) unsigned gas_u32;
typedef __attribute__((address_space(3))) unsigned las_u32;

__device__ __forceinline__ unsigned pk2(float lo, float hi) {
  union { __hip_bfloat162 h2; unsigned u; } c;
  c.h2 = __float22bfloat162_rn(make_float2(lo, hi));  // v_cvt_pk_bf16_f32
  return c.u;
}
__device__ __forceinline__ ushort f2bf1(float f) {
  union { __hip_bfloat16 h; ushort u; } c;
  c.h = __float2bfloat16(f);
  return c.u;
}
__device__ __forceinline__ float u2f(unsigned u) {
  union { unsigned u; float f; } c; c.u = u; return c.f;
}

// ws layout: [0,128K) wpk bf16 A-frags; [128K,+2K) biases f32; [136K,+128K) latpk bf16
__global__ void pack_all(const float* __restrict__ W0, const float* __restrict__ W1,
                         const float* __restrict__ W2, const float* __restrict__ W3,
                         const float* __restrict__ b0, const float* __restrict__ b1,
                         const float* __restrict__ b2, const float* __restrict__ b3,
                         const float* __restrict__ lat,
                         ushort* __restrict__ wpk, float* __restrict__ biasf,
                         ushort* __restrict__ latpk) {
  int t = blockIdx.x * 256 + threadIdx.x;
  if (t < 8192) {
    int lane = t & 63, kt = (t >> 6) & 3, jt = (t >> 8) & 7, layer = t >> 11;
    const float* W = layer == 0 ? W0 : layer == 1 ? W1 : layer == 2 ? W2 : W3;
    int K = (layer == 0) ? 127 : 128;
    int g = lane >> 4, r = lane & 15;
    bf16x8 pk;
#pragma unroll
    for (int i = 0; i < 8; i++) {
      int k = kt * 32 + 8 * g + i;
      pk[i] = (short)((k < K) ? f2bf1(W[k * 128 + jt * 16 + r]) : (ushort)0);
    }
    *(bf16x8*)(wpk + ((t >> 11) * 32 + (jt * 4 + kt)) * 512 + lane * 8) = pk;
  } else if (t < 16384) {
    int t2 = t - 8192;
    int g = t2 & 7, pix = (t2 >> 3) & 255, b = t2 >> 11;
    uint4 w;
    unsigned* wp = &w.x;
#pragma unroll
    for (int i = 0; i < 4; i++)
      wp[i] = pk2(lat[(b * 64 + 8 * g + 2 * i) * 256 + pix],
                  lat[(b * 64 + 8 * g + 2 * i + 1) * 256 + pix]);
    *(uint4*)((char*)latpk + b * 32768 + pix * 128 + ((16 * g) ^ ((pix & 7) << 4))) = w;
  } else if (t < 16896) {
    int t3 = t - 16384;
    int layer = t3 >> 7, j = t3 & 127;
    const float* b = layer == 0 ? b0 : layer == 1 ? b1 : layer == 2 ? b2 : b3;
    biasf[t3] = b[j];
  }
}

__global__ __launch_bounds__(256, 4) void scene_fwd(
    const float* __restrict__ xyz, const ushort* __restrict__ latpk,
    const ushort* __restrict__ wpk, const float* __restrict__ biasf,
    const float* __restrict__ wa, const float* __restrict__ ba,
    float* __restrict__ out) {
  // 32 KB LDS. Phase A: bf16 latent tile via global_load_lds (swizzle
  // pre-applied in latpk). Phase B: 2 h-tiles h[64 pts][128 ch] bf16.
  // 128 points/block. Feature phase SYMMETRIC split per point:
  //   thread A (tid<128):  latent ch 0-31 (16 ds reads) + feat idx 0-31
  //   thread B (tid>=128): latent ch 32-63 (16 ds reads) + feat idx 32-63
  // PE via direct __sinf/__cosf (exact match to verified R11 numerics).
  // MLP: wave w -> tile (w>>1), j-half (w&1); acc[4][4] = 64 f32 AGPR;
  // 64 VGPR + 64 AGPR = 128 -> 16 waves/CU tier.
  __shared__ char smem[32768];
  const int tid = threadIdx.x;
  const int wave = tid >> 6, lane = tid & 63;
  const int g = lane >> 4, r = lane & 15;
  const int p0 = blockIdx.x * 128;
  const int batch = blockIdx.x >> 9;  // 512 blocks per batch

  // ---- hoisted xyz load (latency hides under the stage) ----
  const int t2 = tid & 127;
  const int p = p0 + t2;
  const float X = xyz[3 * p + 0], Y = xyz[3 * p + 1], Z = xyz[3 * p + 2];

  // ---- stage bf16 latent tile: direct global->LDS DMA, linear ----
  {
    const char* src = (const char*)latpk + batch * 32768;
#pragma unroll
    for (int i = 0; i < 8; i++) {
      const int off = (wave * 8 + i) * 1024;
      __builtin_amdgcn_global_load_lds((gas_u32*)(src + off + lane * 16),
                                       (las_u32*)(smem + off), 16, 0, 0);
    }
  }

  // ---- per-point setup (shared by both halves): bilinear + coords ----
  float gx = (X + 1.f) * 8.f - 0.5f;
  float gy = (Z + 1.f) * 8.f - 0.5f;
  float x0f = floorf(gx), y0f = floorf(gy);
  float fx = gx - x0f, fy = gy - y0f;
  int ix0 = (int)x0f, iy0 = (int)y0f;
  int ix1 = ix0 + 1, iy1 = iy0 + 1;
  float vx0 = (ix0 >= 0 && ix0 <= 15) ? 1.f : 0.f;
  float vx1 = (ix1 >= 0 && ix1 <= 15) ? 1.f : 0.f;
  float vy0 = (iy0 >= 0 && iy0 <= 15) ? 1.f : 0.f;
  float vy1 = (iy1 >= 0 && iy1 <= 15) ? 1.f : 0.f;
  int cx0 = min(max(ix0, 0), 15), cx1 = min(max(ix1, 0), 15);
  int cy0 = min(max(iy0, 0), 15), cy1 = min(max(iy1, 0), 15);
  float w00 = (1.f - fx) * (1.f - fy) * vx0 * vy0;
  float w01 = (1.f - fx) * fy * vx0 * vy1;
  float w10 = fx * (1.f - fy) * vx1 * vy0;
  float w11 = fx * fy * vx1 * vy1;
  int px00 = cy0 * 16 + cx0, px01 = cy1 * 16 + cx0;
  int px10 = cy0 * 16 + cx1, px11 = cy1 * 16 + cx1;
  int o00 = px00 * 128, s00b = (px00 & 7) << 4;
  int o01 = px01 * 128, s01b = (px01 & 7) << 4;
  int o10 = px10 * 128, s10b = (px10 & 7) << 4;
  int o11 = px11 * 128, s11b = (px11 & 7) << 4;
  // local coords for PE
  float px_ = (X + 1.f) * 8.f; px_ = px_ - rintf(px_ - 0.5f); px_ = px_ * 2.f - 1.f;
  float pz_ = (Z + 1.f) * 8.f; pz_ = pz_ - rintf(pz_ - 0.5f); pz_ = pz_ * 2.f - 1.f;
  const float py_ = Y;

  __syncthreads();  // stage vmcnt drained; latent tile ready

  // ---- gather: 4 granules (16B each) of latent channels ----
  const int gbase = (tid < 128) ? 0 : 4;  // A: ch 0-31; B: ch 32-63
  uint4 frg[4];
#pragma unroll
  for (int j = 0; j < 4; j++) {
    const int off = 16 * (gbase + j);
    f32x2 f2[4];
#pragma unroll
    for (int q = 0; q < 4; q++) f2[q] = (f32x2){0.f, 0.f};
#pragma unroll
    for (int c = 0; c < 4; c++) {
      const char* ap = smem + (c == 0 ? o00 + (off ^ s00b) : c == 1 ? o01 + (off ^ s01b)
                             : c == 2 ? o10 + (off ^ s10b) : o11 + (off ^ s11b));
      const float wc = c == 0 ? w00 : c == 1 ? w01 : c == 2 ? w10 : w11;
      uint4 cv = *(const uint4*)ap;
      const unsigned* u = &cv.x;
#pragma unroll
      for (int q = 0; q < 4; q++) {
        f32x2 cw = {u2f(u[q] << 16), u2f(u[q] & 0xffff0000u)};
        f2[q] += cw * wc;
      }
    }
    frg[j].x = pk2(f2[0][0], f2[0][1]); frg[j].y = pk2(f2[1][0], f2[1][1]);
    frg[j].z = pk2(f2[2][0], f2[2][1]); frg[j].w = pk2(f2[3][0], f2[3][1]);
  }

  // ---- PE half via direct __sinf/__cosf (identical numerics to R11) ----
  // feat layout: [0..2]=coords, 3+3f+d = sin(cc[d]*2^f), 33+3f+d = cos, 63=0
  uint4 pe[4];
  {
    const int base = (tid < 128) ? 0 : 32;
#pragma unroll
    for (int gi = 0; gi < 4; gi++) {
      unsigned* wo = &pe[gi].x;
#pragma unroll
      for (int q = 0; q < 4; q++) {
        float e[2];
#pragma unroll
        for (int h = 0; h < 2; h++) {
          const int idx = base + 8 * gi + 2 * q + h;
          float v;
          if (idx == 0) v = px_;
          else if (idx == 1) v = py_;
          else if (idx == 2) v = pz_;
          else if (idx == 63) v = 0.f;
          else if (idx < 33) {
            const int s = idx - 3;
            const int d = s % 3;
            const float cc = d == 0 ? px_ : d == 1 ? py_ : pz_;
            v = __sinf(cc * (float)(1 << (s / 3)));
          } else {
            const int s = idx - 33;
            const int d = s % 3;
            const float cc = d == 0 ? px_ : d == 1 ? py_ : pz_;
            v = __cosf(cc * (float)(1 << (s / 3)));
          }
          e[h] = v;
        }
        wo[q] = pk2(e[0], e[1]);
      }
    }
  }
  __syncthreads();  // all gathers done before latent tile is overwritten

  // ---- write h rows (swizzled): 4 latent granules + 4 PE granules ----
  {
    const int tile = t2 >> 6, row = t2 & 63;
    char* rowp = smem + tile * 16384 + row * 256;
    const unsigned swz = (unsigned)((row & 7) << 4);
#pragma unroll
    for (int j = 0; j < 4; j++)
      *(uint4*)(rowp + (((unsigned)(16 * (gbase + j))) ^ swz)) = frg[j];
    const int peg = (tid < 128) ? 8 : 12;
#pragma unroll
    for (int j = 0; j < 4; j++)
      *(uint4*)(rowp + (((unsigned)(16 * (peg + j))) ^ swz)) = pe[j];
  }
  __syncthreads();

  // ---- MLP, j-split: wave covers 64 points x 64 output channels ----
  const int tileM = wave >> 1;
  const int jh = wave & 1;
  char* hb = smem + tileM * 16384;
  f32x4 acc[4][4];
#pragma unroll 1
  for (int layer = 0; layer < 4; layer++) {
    const float* bias = biasf + layer * 128;
    const ushort* Aw = wpk + layer * 16384;
#pragma unroll
    for (int jt = 0; jt < 4; jt++) {
      f32x4 bf = *(const f32x4*)(bias + (jh * 4 + jt) * 16 + 4 * g);
#pragma unroll
      for (int pt = 0; pt < 4; pt++) acc[jt][pt] = bf;
    }
#pragma unroll
    for (int kt = 0; kt < 4; kt++) {
      bf16x8 Bf[4];
#pragma unroll
      for (int pt = 0; pt < 4; pt++) {
        const int pr = pt * 16 + r;
        Bf[pt] = *(const bf16x8*)(hb + pr * 256 +
                  (((unsigned)(kt * 64 + 16 * g)) ^ ((unsigned)((pr & 7) << 4))));
      }
      __builtin_amdgcn_s_setprio(1);
#pragma unroll
      for (int jt = 0; jt < 4; jt++) {
        bf16x8 Af = *(const bf16x8*)(Aw + ((jh * 4 + jt) * 4 + kt) * 512 + lane * 8);
#pragma unroll
        for (int pt = 0; pt < 4; pt++)
          acc[jt][pt] = __builtin_amdgcn_mfma_f32_16x16x32_bf16(Af, Bf[pt], acc[jt][pt], 0, 0, 0);
      }
      __builtin_amdgcn_s_setprio(0);
    }
    if (layer < 3) {
      __syncthreads();  // all reads of h complete before overwrite
#pragma unroll
      for (int jt = 0; jt < 4; jt++) {
#pragma unroll
        for (int pt = 0; pt < 4; pt++) {
          const int pr = pt * 16 + r;
          uint2 w;
          w.x = pk2(fmaxf(acc[jt][pt][0], 0.f), fmaxf(acc[jt][pt][1], 0.f));
          w.y = pk2(fmaxf(acc[jt][pt][2], 0.f), fmaxf(acc[jt][pt][3], 0.f));
          *(uint2*)(hb + pr * 256 +
                    (((unsigned)(32 * (jh * 4 + jt) + 8 * g)) ^ ((unsigned)((pr & 7) << 4)))) = w;
        }
      }
      __syncthreads();  // writes visible before next layer's reads
    }
  }

  // ---- alpha: partial over this wave's j-half, then cross-wave combine ----
  const float ba0 = ba[0];
  float part[4] = {0.f, 0.f, 0.f, 0.f};
#pragma unroll
  for (int jt = 0; jt < 4; jt++) {
    f32x4 wf = *(const f32x4*)(wa + (jh * 4 + jt) * 16 + 4 * g);
#pragma unroll
    for (int pt = 0; pt < 4; pt++) {
#pragma unroll
      for (int i = 0; i < 4; i++)
        part[pt] += fmaxf(acc[jt][pt][i], 0.f) * wf[i];
    }
  }
  __syncthreads();  // layer-3 h reads done everywhere; scr region is free
  float* scr = (float*)smem;  // 1 KB scratch
#pragma unroll
  for (int pt = 0; pt < 4; pt++) {
    float s = part[pt];
    s += __shfl_xor(s, 16, 64);
    s += __shfl_xor(s, 32, 64);
    if (lane < 16) scr[(tileM * 2 + jh) * 64 + pt * 16 + lane] = s;
  }
  __syncthreads();
  if (jh == 0 && lane < 16) {
#pragma unroll
    for (int pt = 0; pt < 4; pt++) {
      const int idx = pt * 16 + lane;
      out[p0 + tileM * 64 + idx] =
          scr[(tileM * 2) * 64 + idx] + scr[(tileM * 2 + 1) * 64 + idx] + ba0;
    }
  }
}

extern "C" void kernel_launch(void* const* d_in, const int* in_sizes, int n_in,
                              void* d_out, int out_size, void* d_ws, size_t ws_size,
                              hipStream_t stream) {
  const float* xyz = (const float*)d_in[0];
  const float* lat = (const float*)d_in[1];
  const float* W0 = (const float*)d_in[2];
  const float* b0 = (const float*)d_in[3];
  const float* W1 = (const float*)d_in[4];
  const float* b1 = (const float*)d_in[5];
  const float* W2 = (const float*)d_in[6];
  const float* b2 = (const float*)d_in[7];
  const float* W3 = (const float*)d_in[8];
  const float* b3 = (const float*)d_in[9];
  const float* wa = (const float*)d_in[10];
  const float* ba = (const float*)d_in[11];
  float* out = (float*)d_out;
  ushort* wpk = (ushort*)d_ws;                       // 128 KB packed weights
  float* biasf = (float*)((char*)d_ws + 131072);     // 2 KB biases
  ushort* latpk = (ushort*)((char*)d_ws + 139264);   // 128 KB packed bf16 latents

  pack_all<<<66, 256, 0, stream>>>(W0, W1, W2, W3, b0, b1, b2, b3, lat,
                                   wpk, biasf, latpk);
  scene_fwd<<<2048, 256, 0, stream>>>(xyz, latpk, wpk, biasf, wa, ba, out);
}

// Round 14
// 52.454 us; speedup vs baseline: 1.0749x; 1.0749x over previous
//
#include <hip/hip_runtime.h>
#include <hip/hip_bf16.h>

typedef float f32x4 __attribute__((ext_vector_type(4)));
typedef float f32x2 __attribute__((ext_vector_type(2)));
typedef short bf16x8 __attribute__((ext_vector_type(8)));
typedef const __attribute__((address_space(1))) unsigned gas_u32;
typedef __attribute__((address_space(3))) unsigned las_u32;

__device__ __forceinline__ unsigned pk2(float lo, float hi) {
  union { __hip_bfloat162 h2; unsigned u; } c;
  c.h2 = __float22bfloat162_rn(make_float2(lo, hi));  // v_cvt_pk_bf16_f32
  return c.u;
}
__device__ __forceinline__ ushort f2bf1(float f) {
  union { __hip_bfloat16 h; ushort u; } c;
  c.h = __float2bfloat16(f);
  return c.u;
}
__device__ __forceinline__ float u2f(unsigned u) {
  union { unsigned u; float f; } c; c.u = u; return c.f;
}

// ws layout: [0,128K) wpk bf16 A-frags; [128K,+2K) biases f32; [136K,+128K) latpk bf16
__global__ void pack_all(const float* __restrict__ W0, const float* __restrict__ W1,
                         const float* __restrict__ W2, const float* __restrict__ W3,
                         const float* __restrict__ b0, const float* __restrict__ b1,
                         const float* __restrict__ b2, const float* __restrict__ b3,
                         const float* __restrict__ lat,
                         ushort* __restrict__ wpk, float* __restrict__ biasf,
                         ushort* __restrict__ latpk) {
  int t = blockIdx.x * 256 + threadIdx.x;
  if (t < 8192) {
    int lane = t & 63, kt = (t >> 6) & 3, jt = (t >> 8) & 7, layer = t >> 11;
    const float* W = layer == 0 ? W0 : layer == 1 ? W1 : layer == 2 ? W2 : W3;
    int K = (layer == 0) ? 127 : 128;
    int g = lane >> 4, r = lane & 15;
    bf16x8 pk;
#pragma unroll
    for (int i = 0; i < 8; i++) {
      int k = kt * 32 + 8 * g + i;
      pk[i] = (short)((k < K) ? f2bf1(W[k * 128 + jt * 16 + r]) : (ushort)0);
    }
    *(bf16x8*)(wpk + ((t >> 11) * 32 + (jt * 4 + kt)) * 512 + lane * 8) = pk;
  } else if (t < 16384) {
    int t2 = t - 8192;
    int g = t2 & 7, pix = (t2 >> 3) & 255, b = t2 >> 11;
    uint4 w;
    unsigned* wp = &w.x;
#pragma unroll
    for (int i = 0; i < 4; i++)
      wp[i] = pk2(lat[(b * 64 + 8 * g + 2 * i) * 256 + pix],
                  lat[(b * 64 + 8 * g + 2 * i + 1) * 256 + pix]);
    *(uint4*)((char*)latpk + b * 32768 + pix * 128 + ((16 * g) ^ ((pix & 7) << 4))) = w;
  } else if (t < 16896) {
    int t3 = t - 16384;
    int layer = t3 >> 7, j = t3 & 127;
    const float* b = layer == 0 ? b0 : layer == 1 ? b1 : layer == 2 ? b2 : b3;
    biasf[t3] = b[j];
  }
}

__global__ __launch_bounds__(256, 4) void scene_fwd(
    const float* __restrict__ xyz, const ushort* __restrict__ latpk,
    const ushort* __restrict__ wpk, const float* __restrict__ biasf,
    const float* __restrict__ wa, const float* __restrict__ ba,
    float* __restrict__ out) {
  // 32 KB LDS. Phase A: bf16 latent tile via global_load_lds (swizzle
  // pre-applied in latpk). Phase B: 2 h-tiles h[64 pts][128 ch] bf16.
  // 128 points/block. MLP: wave w -> tile (w>>1), j-half (w&1):
  // acc[4][4] = 64 f32 in AGPR (16 independent MFMA chains for ILP);
  // 64 VGPR + 64 AGPR = 128 -> 16 waves/CU tier.
  __shared__ char smem[32768];
  const int tid = threadIdx.x;
  const int wave = tid >> 6, lane = tid & 63;
  const int g = lane >> 4, r = lane & 15;
  const int p0 = blockIdx.x * 128;
  const int batch = blockIdx.x >> 9;  // 512 blocks per batch

  // ---- hoisted xyz load (latency hides under the stage) ----
  const int t2 = tid & 127;
  const int p = p0 + t2;
  const float X = xyz[3 * p + 0], Y = xyz[3 * p + 1], Z = xyz[3 * p + 2];

  // ---- stage bf16 latent tile: direct global->LDS DMA, linear ----
  {
    const char* src = (const char*)latpk + batch * 32768;
#pragma unroll
    for (int i = 0; i < 8; i++) {
      const int off = (wave * 8 + i) * 1024;
      __builtin_amdgcn_global_load_lds((gas_u32*)(src + off + lane * 16),
                                       (las_u32*)(smem + off), 16, 0, 0);
    }
  }
  __syncthreads();  // vmcnt drained before barrier

  // ---- features: threads 0-127 gather latents (ch 0-63) for point tid;
  //      threads 128-255 compute PE (ch 64-127) for point tid-128 ----
  uint4 fr[8];  // this thread's 64 channels, bf16-packed
  if (tid < 128) {
    float gx = (X + 1.f) * 8.f - 0.5f;
    float gy = (Z + 1.f) * 8.f - 0.5f;
    float x0f = floorf(gx), y0f = floorf(gy);
    float fx = gx - x0f, fy = gy - y0f;
    int ix0 = (int)x0f, iy0 = (int)y0f;
    int ix1 = ix0 + 1, iy1 = iy0 + 1;
    float vx0 = (ix0 >= 0 && ix0 <= 15) ? 1.f : 0.f;
    float vx1 = (ix1 >= 0 && ix1 <= 15) ? 1.f : 0.f;
    float vy0 = (iy0 >= 0 && iy0 <= 15) ? 1.f : 0.f;
    float vy1 = (iy1 >= 0 && iy1 <= 15) ? 1.f : 0.f;
    int cx0 = min(max(ix0, 0), 15), cx1 = min(max(ix1, 0), 15);
    int cy0 = min(max(iy0, 0), 15), cy1 = min(max(iy1, 0), 15);
    float w00 = (1.f - fx) * (1.f - fy) * vx0 * vy0;
    float w01 = (1.f - fx) * fy * vx0 * vy1;
    float w10 = fx * (1.f - fy) * vx1 * vy0;
    float w11 = fx * fy * vx1 * vy1;
    int px00 = cy0 * 16 + cx0, px01 = cy1 * 16 + cx0;
    int px10 = cy0 * 16 + cx1, px11 = cy1 * 16 + cx1;
    int o00 = px00 * 128, s00 = (px00 & 7) << 4;
    int o01 = px01 * 128, s01 = (px01 & 7) << 4;
    int o10 = px10 * 128, s10 = (px10 & 7) << 4;
    int o11 = px11 * 128, s11 = (px11 & 7) << 4;
    // packed f32x2 blend (candidate v_pk_fma_f32), corner-at-a-time
#pragma unroll
    for (int gr = 0; gr < 8; gr++) {
      const int off = 16 * gr;
      f32x2 f2[4];
#pragma unroll
      for (int q = 0; q < 4; q++) f2[q] = (f32x2){0.f, 0.f};
#pragma unroll
      for (int c = 0; c < 4; c++) {
        const char* ap = smem + (c == 0 ? o00 + (off ^ s00) : c == 1 ? o01 + (off ^ s01)
                               : c == 2 ? o10 + (off ^ s10) : o11 + (off ^ s11));
        const float wc = c == 0 ? w00 : c == 1 ? w01 : c == 2 ? w10 : w11;
        uint4 cv = *(const uint4*)ap;
        const unsigned* u = &cv.x;
#pragma unroll
        for (int q = 0; q < 4; q++) {
          f32x2 cw = {u2f(u[q] << 16), u2f(u[q] & 0xffff0000u)};
          f2[q] += cw * wc;
        }
      }
      fr[gr].x = pk2(f2[0][0], f2[0][1]); fr[gr].y = pk2(f2[1][0], f2[1][1]);
      fr[gr].z = pk2(f2[2][0], f2[2][1]); fr[gr].w = pk2(f2[3][0], f2[3][1]);
    }
  } else {
    // PE pair-on-the-fly (no feat[64] buffer)
    float lcx = (X + 1.f) * 8.f; lcx = lcx - rintf(lcx - 0.5f); lcx = lcx * 2.f - 1.f;
    float lcz = (Z + 1.f) * 8.f; lcz = lcz - rintf(lcz - 0.5f); lcz = lcz * 2.f - 1.f;
    const float c0 = lcx, c1 = Y, c2 = lcz;
#pragma unroll
    for (int gr = 0; gr < 8; gr++) {
      unsigned* wo = &fr[gr].x;
#pragma unroll
      for (int q = 0; q < 4; q++) {
        float e[2];
#pragma unroll
        for (int h = 0; h < 2; h++) {
          const int idx = 8 * gr + 2 * q + h;
          float v;
          if (idx == 0) v = c0;
          else if (idx == 1) v = c1;
          else if (idx == 2) v = c2;
          else if (idx == 63) v = 0.f;
          else if (idx < 33) {
            const int s = idx - 3;
            const int d = s % 3;
            const float cc = d == 0 ? c0 : d == 1 ? c1 : c2;
            v = __sinf(cc * (float)(1 << (s / 3)));
          } else {
            const int s = idx - 33;
            const int d = s % 3;
            const float cc = d == 0 ? c0 : d == 1 ? c1 : c2;
            v = __cosf(cc * (float)(1 << (s / 3)));
          }
          e[h] = v;
        }
        wo[q] = pk2(e[0], e[1]);
      }
    }
  }
  __syncthreads();  // all gathers done before latent tile is overwritten

  // ---- write h rows (swizzled) ----
  {
    const int tile = t2 >> 6, row = t2 & 63;
    char* rowp = smem + tile * 16384 + row * 256;
    const unsigned swz = (unsigned)((row & 7) << 4);
    const int base = (tid < 128) ? 0 : 128;
#pragma unroll
    for (int gr = 0; gr < 8; gr++)
      *(uint4*)(rowp + (((unsigned)(base + 16 * gr)) ^ swz)) = fr[gr];
  }
  __syncthreads();

  // ---- MLP, j-split: wave covers 64 points x 64 output channels ----
  const int tileM = wave >> 1;
  const int jh = wave & 1;
  char* hb = smem + tileM * 16384;
  f32x4 acc[4][4];
#pragma unroll 1
  for (int layer = 0; layer < 4; layer++) {
    const float* bias = biasf + layer * 128;
    const ushort* Aw = wpk + layer * 16384;
#pragma unroll
    for (int jt = 0; jt < 4; jt++) {
      f32x4 bf = *(const f32x4*)(bias + (jh * 4 + jt) * 16 + 4 * g);
#pragma unroll
      for (int pt = 0; pt < 4; pt++) acc[jt][pt] = bf;
    }
#pragma unroll
    for (int kt = 0; kt < 4; kt++) {
      bf16x8 Bf[4];
#pragma unroll
      for (int pt = 0; pt < 4; pt++) {
        const int pr = pt * 16 + r;
        Bf[pt] = *(const bf16x8*)(hb + pr * 256 +
                  (((unsigned)(kt * 64 + 16 * g)) ^ ((unsigned)((pr & 7) << 4))));
      }
      __builtin_amdgcn_s_setprio(1);
#pragma unroll
      for (int jt = 0; jt < 4; jt++) {
        bf16x8 Af = *(const bf16x8*)(Aw + ((jh * 4 + jt) * 4 + kt) * 512 + lane * 8);
#pragma unroll
        for (int pt = 0; pt < 4; pt++)
          acc[jt][pt] = __builtin_amdgcn_mfma_f32_16x16x32_bf16(Af, Bf[pt], acc[jt][pt], 0, 0, 0);
      }
      __builtin_amdgcn_s_setprio(0);
    }
    if (layer < 3) {
      __syncthreads();  // all reads of h complete before overwrite
#pragma unroll
      for (int jt = 0; jt < 4; jt++) {
#pragma unroll
        for (int pt = 0; pt < 4; pt++) {
          const int pr = pt * 16 + r;
          uint2 w;
          w.x = pk2(fmaxf(acc[jt][pt][0], 0.f), fmaxf(acc[jt][pt][1], 0.f));
          w.y = pk2(fmaxf(acc[jt][pt][2], 0.f), fmaxf(acc[jt][pt][3], 0.f));
          *(uint2*)(hb + pr * 256 +
                    (((unsigned)(32 * (jh * 4 + jt) + 8 * g)) ^ ((unsigned)((pr & 7) << 4)))) = w;
        }
      }
      __syncthreads();  // writes visible before next layer's reads
    }
  }

  // ---- alpha: partial over this wave's j-half, then cross-wave combine ----
  const float ba0 = ba[0];
  float part[4] = {0.f, 0.f, 0.f, 0.f};
#pragma unroll
  for (int jt = 0; jt < 4; jt++) {
    f32x4 wf = *(const f32x4*)(wa + (jh * 4 + jt) * 16 + 4 * g);
#pragma unroll
    for (int pt = 0; pt < 4; pt++) {
#pragma unroll
      for (int i = 0; i < 4; i++)
        part[pt] += fmaxf(acc[jt][pt][i], 0.f) * wf[i];
    }
  }
  __syncthreads();  // layer-3 h reads done everywhere; scr region is free
  float* scr = (float*)smem;  // 1 KB scratch
#pragma unroll
  for (int pt = 0; pt < 4; pt++) {
    float s = part[pt];
    s += __shfl_xor(s, 16, 64);
    s += __shfl_xor(s, 32, 64);
    if (lane < 16) scr[(tileM * 2 + jh) * 64 + pt * 16 + lane] = s;
  }
  __syncthreads();
  if (jh == 0 && lane < 16) {
#pragma unroll
    for (int pt = 0; pt < 4; pt++) {
      const int idx = pt * 16 + lane;
      out[p0 + tileM * 64 + idx] =
          scr[(tileM * 2) * 64 + idx] + scr[(tileM * 2 + 1) * 64 + idx] + ba0;
    }
  }
}

extern "C" void kernel_launch(void* const* d_in, const int* in_sizes, int n_in,
                              void* d_out, int out_size, void* d_ws, size_t ws_size,
                              hipStream_t stream) {
  const float* xyz = (const float*)d_in[0];
  const float* lat = (const float*)d_in[1];
  const float* W0 = (const float*)d_in[2];
  const float* b0 = (const float*)d_in[3];
  const float* W1 = (const float*)d_in[4];
  const float* b1 = (const float*)d_in[5];
  const float* W2 = (const float*)d_in[6];
  const float* b2 = (const float*)d_in[7];
  const float* W3 = (const float*)d_in[8];
  const float* b3 = (const float*)d_in[9];
  const float* wa = (const float*)d_in[10];
  const float* ba = (const float*)d_in[11];
  float* out = (float*)d_out;
  ushort* wpk = (ushort*)d_ws;                       // 128 KB packed weights
  float* biasf = (float*)((char*)d_ws + 131072);     // 2 KB biases
  ushort* latpk = (ushort*)((char*)d_ws + 139264);   // 128 KB packed bf16 latents

  pack_all<<<66, 256, 0, stream>>>(W0, W1, W2, W3, b0, b1, b2, b3, lat,
                                   wpk, biasf, latpk);
  scene_fwd<<<2048, 256, 0, stream>>>(xyz, latpk, wpk, biasf, wa, ba, out);
}